// Round 10
// baseline (1613.697 us; speedup 1.0000x reference)
//
#include <hip/hip_runtime.h>
#include <hip/hip_bf16.h>

typedef __hip_bfloat16 bf16;
typedef __bf16 bf16x8 __attribute__((ext_vector_type(8)));
typedef __bf16 bf16x4 __attribute__((ext_vector_type(4)));
typedef __bf16 bf16x2 __attribute__((ext_vector_type(2)));
typedef float f32x4 __attribute__((ext_vector_type(4)));

static constexpr int Bq = 4, Tq = 2048, Dq = 1024;
static constexpr int NBLK = 768;   // persistent grid; __launch_bounds__(256,3) guarantees 3 blocks/CU co-residency

__device__ inline float b2f(bf16 h) { return __bfloat162float(h); }
__device__ inline bf16 f2b(float f) { return __float2bfloat16(f); }

__device__ __forceinline__ void gload_lds16(const bf16* g, bf16* lds_wave_base) {
    __builtin_amdgcn_global_load_lds((const __attribute__((address_space(1))) void*)g,
                                     (__attribute__((address_space(3))) void*)lds_wave_base,
                                     16, 0, 0);
}

__device__ __forceinline__ float fast_gelu(float x) {
    float u = x * (0.7978845608028654f + 0.03567740814183427f * x * x);
    float e = __builtin_amdgcn_exp2f(-2.885390081777927f * u);
    return x * __builtin_amdgcn_rcpf(1.f + e);
}

__device__ inline void ld4f(const float* p, float* v) {
    float4 t = *reinterpret_cast<const float4*>(p);
    v[0] = t.x; v[1] = t.y; v[2] = t.z; v[3] = t.w;
}
__device__ inline void ld4f(const bf16* p, float* v) {
    bf16x4 t = *reinterpret_cast<const bf16x4*>(p);
    v[0] = (float)t[0]; v[1] = (float)t[1]; v[2] = (float)t[2]; v[3] = (float)t[3];
}

// ---------------- device-scope grid barrier (generation counter) ----------------
// bar[0] = arrive count, bar[1] = generation. prep initializes both to 0 each call.
__device__ __forceinline__ void grid_sync(unsigned* bar) {
    __syncthreads();
    if (threadIdx.x == 0) {
        __threadfence();
        unsigned g = __hip_atomic_load(bar + 1, __ATOMIC_RELAXED, __HIP_MEMORY_SCOPE_AGENT);
        unsigned a = __hip_atomic_fetch_add(bar, 1u, __ATOMIC_ACQ_REL, __HIP_MEMORY_SCOPE_AGENT);
        if (a == NBLK - 1u) {
            __hip_atomic_store(bar, 0u, __ATOMIC_RELAXED, __HIP_MEMORY_SCOPE_AGENT);
            __hip_atomic_fetch_add(bar + 1, 1u, __ATOMIC_RELEASE, __HIP_MEMORY_SCOPE_AGENT);
        } else {
            while (__hip_atomic_load(bar + 1, __ATOMIC_ACQUIRE, __HIP_MEMORY_SCOPE_AGENT) == g)
                __builtin_amdgcn_s_sleep(2);
        }
        __threadfence();
    }
    __syncthreads();
}

// ---------------- LayerNorm body (one 256-thread pass per row, D=1024) ----------------
template <typename Tin>
__device__ __forceinline__ void ln_body(const Tin* __restrict__ x, const float* __restrict__ g,
                                        const float* __restrict__ b, bf16* __restrict__ out,
                                        int row, float* sred)
{
    const int tid = threadIdx.x;
    const int s0 = tid * 4;
    const Tin* xr = x + (size_t)row * Dq;
    bf16* orow = out + (size_t)row * Dq;
    float v[4], gv[4], bv[4];
    ld4f(xr + s0, v);
    ld4f(g + s0, gv);
    ld4f(b + s0, bv);
    float sum = v[0] + v[1] + v[2] + v[3];
    float sq = v[0]*v[0] + v[1]*v[1] + v[2]*v[2] + v[3]*v[3];
    for (int o = 32; o > 0; o >>= 1) { sum += __shfl_xor(sum, o); sq += __shfl_xor(sq, o); }
    const int w = tid >> 6;
    if ((tid & 63) == 0) { sred[w] = sum; sred[4 + w] = sq; }
    __syncthreads();
    const float ts = sred[0] + sred[1] + sred[2] + sred[3];
    const float tq = sred[4] + sred[5] + sred[6] + sred[7];
    const float mean = ts / Dq;
    const float rs = rsqrtf(tq / Dq - mean * mean + 1e-5f);
    bf16x4 o4;
    #pragma unroll
    for (int i = 0; i < 4; ++i) o4[i] = (__bf16)((v[i] - mean) * rs * gv[i] + bv[i]);
    *reinterpret_cast<bf16x4*>(orow + s0) = o4;
}

// ---------------- prep: LN1 (8192) + 4 weight transposes (3072 tiles) + barrier init ----------------
__global__ void prep_kernel(const float* __restrict__ x, const float* __restrict__ g,
                            const float* __restrict__ b, bf16* __restrict__ h,
                            const float* __restrict__ Wqkv, bf16* __restrict__ WqkvT,
                            const float* __restrict__ Wproj, bf16* __restrict__ WprojT,
                            const float* __restrict__ W1, bf16* __restrict__ W1T,
                            const float* __restrict__ W2, bf16* __restrict__ W2T,
                            unsigned* __restrict__ bar)
{
    __shared__ float smem[64 * 65];
    int id = blockIdx.x;
    if (id == 0 && threadIdx.x == 0) {
        __hip_atomic_store(bar, 0u, __ATOMIC_RELAXED, __HIP_MEMORY_SCOPE_AGENT);
        __hip_atomic_store(bar + 1, 0u, __ATOMIC_RELAXED, __HIP_MEMORY_SCOPE_AGENT);
    }
    if (id < 8192) { ln_body(x, g, b, h, id, smem); return; }
    id -= 8192;
    const float* src; bf16* dst; long ldin, ldout; int gx;
    if (id < 768)       { src = Wqkv;  dst = WqkvT;  ldin = 3072; ldout = 1024; gx = 48; }
    else if (id < 1024) { id -= 768;  src = Wproj; dst = WprojT; ldin = 1024; ldout = 1024; gx = 16; }
    else if (id < 2048) { id -= 1024; src = W1;    dst = W1T;    ldin = 4096; ldout = 1024; gx = 64; }
    else                { id -= 2048; src = W2;    dst = W2T;    ldin = 1024; ldout = 4096; gx = 16; }
    const int c0 = (id % gx) * 64, r0 = (id / gx) * 64;
    const int tid = threadIdx.x;
    const int tx = tid & 63, ty = tid >> 6;
    float (*tile)[65] = reinterpret_cast<float(*)[65]>(smem);
    #pragma unroll
    for (int i = 0; i < 16; ++i) {
        int r = ty + i * 4;
        tile[r][tx] = src[(size_t)(r0 + r) * ldin + c0 + tx];
    }
    __syncthreads();
    const int px = tid & 31, cy = tid >> 5;
    #pragma unroll
    for (int i = 0; i < 8; ++i) {
        int cc = cy + i * 8;
        bf16x2 p;
        p[0] = (__bf16)tile[px * 2][cc];
        p[1] = (__bf16)tile[px * 2 + 1][cc];
        *reinterpret_cast<bf16x2*>(&dst[(size_t)(c0 + cc) * ldout + r0 + px * 2]) = p;
    }
}

// ---------------- XCD-banded tile remap (bijective; gy % 8 == 0) ----------------
__device__ __forceinline__ void band_remap(int lin, int gx, int gy, int& bx, int& by) {
    const int band = lin & 7;
    const int idx = lin >> 3;
    bx = idx % gx;
    by = band * (gy >> 3) + idx / gx;
}

// ---------------- one 128x128 GEMM tile (R8 inner loop: 16x16x32, BK=64, swizzled LDS) ----------------
// ACT: 0 none, 1 gelu, 2 exp2 w/ causal mask. CK: Kend=min(K,m0+128). FR: fused rowsum.
// LDS slot s at row r holds global granule s^(r&7); frag reads conflict-free (R8: 0).
template <int ACT, int CK, int FR>
__device__ __forceinline__ void gemm_tile(const bf16* __restrict__ A, const bf16* __restrict__ Bt,
                                          const float* __restrict__ bias,
                                          bf16* __restrict__ Cb, float* __restrict__ Cf,
                                          int K, long lda, long ldb, long ldc, float scale,
                                          int m0, int n0, bf16* As, bf16* Bs)
{
    const int Kend = CK ? min(K, m0 + 128) : K;
    const int tid = threadIdx.x;
    const int wid = tid >> 6, lane = tid & 63;
    const int wr = wid >> 1, wc = wid & 1;
    const int l15 = lane & 15, quad = lane >> 4;

    const int rloc = lane >> 3, slot = lane & 7;
    const bf16* agp = A + (size_t)(m0 + wid * 32 + rloc) * lda + (slot ^ rloc) * 8;
    const bf16* bgp = Bt + (size_t)(n0 + wid * 32 + rloc) * ldb + (slot ^ rloc) * 8;
    bf16* awb = As + wid * 32 * 64;
    bf16* bwb = Bs + wid * 32 * 64;

    const int afo = (wr * 64 + l15) * 64 + ((quad ^ (l15 & 7)) * 8);
    const int bfo = (wc * 64 + l15) * 64 + ((quad ^ (l15 & 7)) * 8);

    f32x4 acc[4][4];
    #pragma unroll
    for (int i = 0; i < 4; ++i)
        #pragma unroll
        for (int j = 0; j < 4; ++j) acc[i][j] = (f32x4){0.f, 0.f, 0.f, 0.f};

    f32x4 acc_l[4];
    bf16x8 ones;
    if (FR) {
        #pragma unroll
        for (int i = 0; i < 4; ++i) acc_l[i] = (f32x4){0.f, 0.f, 0.f, 0.f};
        #pragma unroll
        for (int i = 0; i < 8; ++i) ones[i] = (__bf16)1.0f;
    }

    for (int k0 = 0; k0 < Kend; k0 += 64) {
        #pragma unroll
        for (int i = 0; i < 4; ++i) {
            gload_lds16(agp + k0 + (size_t)(i * 8) * lda, awb + i * 8 * 64);
            gload_lds16(bgp + k0 + (size_t)(i * 8) * ldb, bwb + i * 8 * 64);
        }
        __syncthreads();

        bf16x8 af0[4], bf0[4], af1[4], bf1[4];
        #pragma unroll
        for (int i = 0; i < 4; ++i) {
            af0[i] = *reinterpret_cast<const bf16x8*>(As + (afo ^ 0)  + i * 1024);
            af1[i] = *reinterpret_cast<const bf16x8*>(As + (afo ^ 32) + i * 1024);
        }
        #pragma unroll
        for (int j = 0; j < 4; ++j) {
            bf0[j] = *reinterpret_cast<const bf16x8*>(Bs + (bfo ^ 0)  + j * 1024);
            bf1[j] = *reinterpret_cast<const bf16x8*>(Bs + (bfo ^ 32) + j * 1024);
        }
        #pragma unroll
        for (int i = 0; i < 4; ++i)
            #pragma unroll
            for (int j = 0; j < 4; ++j)
                acc[i][j] = __builtin_amdgcn_mfma_f32_16x16x32_bf16(af0[i], bf0[j], acc[i][j], 0, 0, 0);
        if (FR) {
            #pragma unroll
            for (int i = 0; i < 4; ++i)
                acc_l[i] = __builtin_amdgcn_mfma_f32_16x16x32_bf16(af0[i], ones, acc_l[i], 0, 0, 0);
        }
        #pragma unroll
        for (int i = 0; i < 4; ++i)
            #pragma unroll
            for (int j = 0; j < 4; ++j)
                acc[i][j] = __builtin_amdgcn_mfma_f32_16x16x32_bf16(af1[i], bf1[j], acc[i][j], 0, 0, 0);
        if (FR) {
            #pragma unroll
            for (int i = 0; i < 4; ++i)
                acc_l[i] = __builtin_amdgcn_mfma_f32_16x16x32_bf16(af1[i], ones, acc_l[i], 0, 0, 0);
        }

        __syncthreads();
    }

    // epilogue: C/D layout row=quad*4+reg, col=l15 (m89/m91-verified)
    #pragma unroll
    for (int i = 0; i < 4; ++i) {
        const int row = m0 + wr * 64 + i * 16 + quad * 4;
        #pragma unroll
        for (int j = 0; j < 4; ++j) {
            const int col = n0 + wc * 64 + j * 16 + l15;
            const float bv = bias ? bias[col] : 0.f;
            #pragma unroll
            for (int r = 0; r < 4; ++r) {
                float vv = scale * acc[i][j][r] + bv;
                if (ACT == 1) vv = fast_gelu(vv);
                else if (ACT == 2)
                    vv = (col <= row + r) ? __builtin_amdgcn_exp2f(1.4426950408889634f * vv) : 0.f;
                if (FR) vv *= __builtin_amdgcn_rcpf(acc_l[i][r]);
                const size_t idx2 = (size_t)(row + r) * ldc + col;
                if (Cf) Cf[idx2] = vv;
                else    Cb[idx2] = f2b(vv);
            }
        }
    }
}

// ---------------- V -> V^T 64x64 tile transpose (within scores phase) ----------------
__device__ __forceinline__ void vtrans_tile(const bf16* __restrict__ ip, bf16* __restrict__ op,
                                            int idx, bf16* smem)
{
    __syncthreads();
    bf16 (*tile)[66] = reinterpret_cast<bf16(*)[66]>(smem);
    const int c0 = (idx & 15) * 64, r0 = (idx >> 4) * 64;
    const int tid = threadIdx.x;
    const int tx = tid & 31, ty = tid >> 5;
    #pragma unroll
    for (int i = 0; i < 8; ++i) {
        int r = ty + i * 8;
        *reinterpret_cast<bf16x2*>(&tile[r][tx * 2]) =
            *reinterpret_cast<const bf16x2*>(&ip[(size_t)(r0 + r) * 3072 + c0 + tx * 2]);
    }
    __syncthreads();
    #pragma unroll
    for (int i = 0; i < 8; ++i) {
        int cc = ty + i * 8;
        bf16x2 p;
        p[0] = tile[tx * 2][cc];
        p[1] = tile[tx * 2 + 1][cc];
        *reinterpret_cast<bf16x2*>(&op[(size_t)(c0 + cc) * 2048 + r0 + tx * 2]) = p;
    }
    __syncthreads();
}

// ---------------- persistent mega-kernel: QKV | scores+vT | attnV | proj | LN2 | MLP1 | MLP2 ----------------
__global__ __launch_bounds__(256, 3)
void mega_kernel(const bf16* __restrict__ h, bf16* __restrict__ kqv, bf16* __restrict__ vT,
                 bf16* __restrict__ attn, bf16* __restrict__ a, bf16* __restrict__ p,
                 bf16* __restrict__ h2, bf16* __restrict__ m, float* __restrict__ out,
                 const bf16* __restrict__ WqkvT, const float* __restrict__ bqkv,
                 const bf16* __restrict__ WprojT, const float* __restrict__ bproj,
                 const float* __restrict__ ln2g, const float* __restrict__ ln2b,
                 const bf16* __restrict__ W1T, const float* __restrict__ b1,
                 const bf16* __restrict__ W2T, const float* __restrict__ b2,
                 unsigned* __restrict__ bar)
{
    __shared__ bf16 As[128 * 64];
    __shared__ bf16 Bs[128 * 64];
    const int blk = blockIdx.x;
    const long T3D = (long)Tq * 3072, TT = (long)Tq * Tq, DT = (long)Dq * Tq, TD = (long)Tq * Dq;

    // P1: kqv = h @ WqkvT + bqkv   (1536 tiles, gx=24 gy=64)
    for (int t = blk; t < 1536; t += NBLK) {
        int bx, by; band_remap(t, 24, 64, bx, by);
        gemm_tile<0,0,0>(h, WqkvT, bqkv, kqv, nullptr, 1024, 1024L, 1024L, 3072L, 1.f,
                         by * 128, bx * 128, As, Bs);
    }
    grid_sync(bar);

    // P2: P-hat = exp(q k^T / sqrt(T)) causal (544 TRI tiles) + V->vT (2048 tiles)
    for (int t = blk; t < 2592; t += NBLK) {
        if (t < 544) {
            const int z = t / 136, lin = t % 136;
            int by = (int)((sqrtf(8.f * lin + 1.f) - 1.f) * 0.5f);
            while ((by + 1) * (by + 2) / 2 <= lin) ++by;
            while (by * (by + 1) / 2 > lin) --by;
            const int bx = lin - by * (by + 1) / 2;
            gemm_tile<2,0,0>(kqv + 1024 + (size_t)z * T3D, kqv + (size_t)z * T3D, nullptr,
                             attn + (size_t)z * TT, nullptr, 1024, 3072L, 3072L, 2048L,
                             0.022097086912079608f, by * 128, bx * 128, As, Bs);
        } else {
            const int j = t - 544, z = j >> 9, idx = j & 511;
            vtrans_tile(kqv + 2048 + (size_t)z * T3D, vT + (size_t)z * DT, idx, As);
        }
    }
    grid_sync(bar);

    // P3: a = (P-hat @ V) * rcp(rowsum)   (512 tiles, per z: gx=8 gy=16)
    if (blk < 512) {
        const int z = blk >> 7, lin = blk & 127;
        int bx, by; band_remap(lin, 8, 16, bx, by);
        gemm_tile<0,1,1>(attn + (size_t)z * TT, vT + (size_t)z * DT, nullptr,
                         a + (size_t)z * TD, nullptr, 2048, 2048L, 2048L, 1024L, 1.f,
                         by * 128, bx * 128, As, Bs);
    }
    grid_sync(bar);

    // P4: p = a @ WprojT + bproj   (512 tiles, gx=8 gy=64)
    if (blk < 512) {
        int bx, by; band_remap(blk, 8, 64, bx, by);
        gemm_tile<0,0,0>(a, WprojT, bproj, p, nullptr, 1024, 1024L, 1024L, 1024L, 1.f,
                         by * 128, bx * 128, As, Bs);
    }
    grid_sync(bar);

    // P5: h2 = LN2(p)   (8192 rows)
    for (int r = blk; r < 8192; r += NBLK) {
        ln_body(p, ln2g, ln2b, h2, r, reinterpret_cast<float*>(As));
        __syncthreads();
    }
    grid_sync(bar);

    // P6: m = gelu(h2 @ W1T + b1)   (2048 tiles, gx=32 gy=64)
    for (int t = blk; t < 2048; t += NBLK) {
        int bx, by; band_remap(t, 32, 64, bx, by);
        gemm_tile<1,0,0>(h2, W1T, b1, m, nullptr, 1024, 1024L, 1024L, 4096L, 1.f,
                         by * 128, bx * 128, As, Bs);
    }
    grid_sync(bar);

    // P7: out = m @ W2T + b2   (512 tiles, gx=8 gy=64, fp32 out)
    if (blk < 512) {
        int bx, by; band_remap(blk, 8, 64, bx, by);
        gemm_tile<0,0,0>(m, W2T, b2, nullptr, out, 4096, 4096L, 4096L, 1024L, 1.f,
                         by * 128, bx * 128, As, Bs);
    }
}

extern "C" void kernel_launch(void* const* d_in, const int* in_sizes, int n_in,
                              void* d_out, int out_size, void* d_ws, size_t ws_size,
                              hipStream_t stream)
{
    (void)in_sizes; (void)n_in; (void)out_size; (void)ws_size;
    const float* x     = (const float*)d_in[0];
    const float* ln1g  = (const float*)d_in[1];
    const float* ln1b  = (const float*)d_in[2];
    const float* Wqkv  = (const float*)d_in[3];
    const float* bqkv  = (const float*)d_in[4];
    const float* Wproj = (const float*)d_in[5];
    const float* bproj = (const float*)d_in[6];
    const float* ln2g  = (const float*)d_in[7];
    const float* ln2b  = (const float*)d_in[8];
    const float* W1    = (const float*)d_in[9];
    const float* b1    = (const float*)d_in[10];
    const float* W2    = (const float*)d_in[11];
    const float* b2    = (const float*)d_in[12];
    float* out = (float*)d_out;

    // ---- workspace arena (bf16 elements) ----
    char* ws = (char*)d_ws;
    size_t off = 0;
    auto alloc = [&](size_t elems) { bf16* p = (bf16*)(ws + off); off += elems * sizeof(bf16); return p; };
    bf16* WqkvT  = alloc(3072UL * 1024);
    bf16* WprojT = alloc(1024UL * 1024);
    bf16* W1T    = alloc(4096UL * 1024);
    bf16* W2T    = alloc(1024UL * 4096);
    bf16* h      = alloc(8192UL * 1024);        // LN1 out; later reused as `a`
    bf16* kqv    = alloc(8192UL * 3072);        // per-row k|q|v
    bf16* vT     = alloc(4UL * 1024 * 2048);
    bf16* attn   = alloc(4UL * 2048 * 2048);    // unnormalized exp'd scores
    unsigned* bar = (unsigned*)alloc(64);       // grid barrier (count, generation)
    // aliases (lifetimes disjoint):
    bf16* a   = h;
    bf16* p   = kqv;
    bf16* h2  = kqv + 8192UL * 1024;
    bf16* m   = kqv + 2UL * 8192 * 1024;        // spans kqv-tail + vT + attn

    // prep: LN1 + all 4 weight transposes + barrier init, one dispatch
    prep_kernel<<<11264, 256, 0, stream>>>(x, ln1g, ln1b, h,
                                           Wqkv, WqkvT, Wproj, WprojT, W1, W1T, W2, W2T, bar);

    // everything else: one persistent kernel with device-scope grid barriers
    mega_kernel<<<NBLK, 256, 0, stream>>>(h, kqv, vT, attn, a, p, h2, m, out,
                                          WqkvT, bqkv, WprojT, bproj, ln2g, ln2b,
                                          W1T, b1, W2T, b2, bar);
}

// Round 11
// 968.332 us; speedup vs baseline: 1.6665x; 1.6665x over previous
//
#include <hip/hip_runtime.h>
#include <hip/hip_bf16.h>

typedef __hip_bfloat16 bf16;
typedef __bf16 bf16x8 __attribute__((ext_vector_type(8)));
typedef __bf16 bf16x4 __attribute__((ext_vector_type(4)));
typedef __bf16 bf16x2 __attribute__((ext_vector_type(2)));
typedef float f32x4 __attribute__((ext_vector_type(4)));

static constexpr int Bq = 4, Tq = 2048, Dq = 1024;
static constexpr int NBLK = 768;   // persistent grid; __launch_bounds__(256,3) guarantees 3 blocks/CU co-residency

__device__ inline float b2f(bf16 h) { return __bfloat162float(h); }
__device__ inline bf16 f2b(float f) { return __float2bfloat16(f); }

__device__ __forceinline__ void gload_lds16(const bf16* g, bf16* lds_wave_base) {
    __builtin_amdgcn_global_load_lds((const __attribute__((address_space(1))) void*)g,
                                     (__attribute__((address_space(3))) void*)lds_wave_base,
                                     16, 0, 0);
}

__device__ __forceinline__ float fast_gelu(float x) {
    float u = x * (0.7978845608028654f + 0.03567740814183427f * x * x);
    float e = __builtin_amdgcn_exp2f(-2.885390081777927f * u);
    return x * __builtin_amdgcn_rcpf(1.f + e);
}

__device__ inline void ld4f(const float* p, float* v) {
    float4 t = *reinterpret_cast<const float4*>(p);
    v[0] = t.x; v[1] = t.y; v[2] = t.z; v[3] = t.w;
}
__device__ inline void ld4f(const bf16* p, float* v) {
    bf16x4 t = *reinterpret_cast<const bf16x4*>(p);
    v[0] = (float)t[0]; v[1] = (float)t[1]; v[2] = (float)t[2]; v[3] = (float)t[3];
}

// ---------------- device-scope grid barrier (generation counter) ----------------
// R10 lesson: ACQUIRE-polling emits an L1/L2 invalidate PER POLL -> cache-invalidation
// storm starves working blocks (MfmaUtil 6.5%, FETCH 2x). Fix: RELAXED polls (no cache
// ops), s_sleep(32), release on arrive, exactly ONE acquire per block after exit.
__device__ __forceinline__ void grid_sync(unsigned* bar) {
    __syncthreads();
    if (threadIdx.x == 0) {
        const unsigned g = __hip_atomic_load(bar + 1, __ATOMIC_RELAXED, __HIP_MEMORY_SCOPE_AGENT);
        const unsigned a = __hip_atomic_fetch_add(bar, 1u, __ATOMIC_RELEASE, __HIP_MEMORY_SCOPE_AGENT);
        if (a == NBLK - 1u) {
            __hip_atomic_store(bar, 0u, __ATOMIC_RELAXED, __HIP_MEMORY_SCOPE_AGENT);
            __hip_atomic_store(bar + 1, g + 1u, __ATOMIC_RELEASE, __HIP_MEMORY_SCOPE_AGENT);
        } else {
            while (__hip_atomic_load(bar + 1, __ATOMIC_RELAXED, __HIP_MEMORY_SCOPE_AGENT) == g)
                __builtin_amdgcn_s_sleep(32);
        }
        // single acquire (one L1/L2 inv) per block per barrier — also the correctness
        // fence making other XCDs' phase-k writes visible.
        (void)__hip_atomic_load(bar + 1, __ATOMIC_ACQUIRE, __HIP_MEMORY_SCOPE_AGENT);
    }
    __syncthreads();
}

// ---------------- LayerNorm body (one 256-thread pass per row, D=1024) ----------------
template <typename Tin>
__device__ __forceinline__ void ln_body(const Tin* __restrict__ x, const float* __restrict__ g,
                                        const float* __restrict__ b, bf16* __restrict__ out,
                                        int row, float* sred)
{
    const int tid = threadIdx.x;
    const int s0 = tid * 4;
    const Tin* xr = x + (size_t)row * Dq;
    bf16* orow = out + (size_t)row * Dq;
    float v[4], gv[4], bv[4];
    ld4f(xr + s0, v);
    ld4f(g + s0, gv);
    ld4f(b + s0, bv);
    float sum = v[0] + v[1] + v[2] + v[3];
    float sq = v[0]*v[0] + v[1]*v[1] + v[2]*v[2] + v[3]*v[3];
    for (int o = 32; o > 0; o >>= 1) { sum += __shfl_xor(sum, o); sq += __shfl_xor(sq, o); }
    const int w = tid >> 6;
    if ((tid & 63) == 0) { sred[w] = sum; sred[4 + w] = sq; }
    __syncthreads();
    const float ts = sred[0] + sred[1] + sred[2] + sred[3];
    const float tq = sred[4] + sred[5] + sred[6] + sred[7];
    const float mean = ts / Dq;
    const float rs = rsqrtf(tq / Dq - mean * mean + 1e-5f);
    bf16x4 o4;
    #pragma unroll
    for (int i = 0; i < 4; ++i) o4[i] = (__bf16)((v[i] - mean) * rs * gv[i] + bv[i]);
    *reinterpret_cast<bf16x4*>(orow + s0) = o4;
}

// ---------------- prep: LN1 (8192) + 4 weight transposes (3072 tiles) + barrier init ----------------
__global__ void prep_kernel(const float* __restrict__ x, const float* __restrict__ g,
                            const float* __restrict__ b, bf16* __restrict__ h,
                            const float* __restrict__ Wqkv, bf16* __restrict__ WqkvT,
                            const float* __restrict__ Wproj, bf16* __restrict__ WprojT,
                            const float* __restrict__ W1, bf16* __restrict__ W1T,
                            const float* __restrict__ W2, bf16* __restrict__ W2T,
                            unsigned* __restrict__ bar)
{
    __shared__ float smem[64 * 65];
    int id = blockIdx.x;
    if (id == 0 && threadIdx.x == 0) {
        __hip_atomic_store(bar, 0u, __ATOMIC_RELAXED, __HIP_MEMORY_SCOPE_AGENT);
        __hip_atomic_store(bar + 1, 0u, __ATOMIC_RELAXED, __HIP_MEMORY_SCOPE_AGENT);
    }
    if (id < 8192) { ln_body(x, g, b, h, id, smem); return; }
    id -= 8192;
    const float* src; bf16* dst; long ldin, ldout; int gx;
    if (id < 768)       { src = Wqkv;  dst = WqkvT;  ldin = 3072; ldout = 1024; gx = 48; }
    else if (id < 1024) { id -= 768;  src = Wproj; dst = WprojT; ldin = 1024; ldout = 1024; gx = 16; }
    else if (id < 2048) { id -= 1024; src = W1;    dst = W1T;    ldin = 4096; ldout = 1024; gx = 64; }
    else                { id -= 2048; src = W2;    dst = W2T;    ldin = 1024; ldout = 4096; gx = 16; }
    const int c0 = (id % gx) * 64, r0 = (id / gx) * 64;
    const int tid = threadIdx.x;
    const int tx = tid & 63, ty = tid >> 6;
    float (*tile)[65] = reinterpret_cast<float(*)[65]>(smem);
    #pragma unroll
    for (int i = 0; i < 16; ++i) {
        int r = ty + i * 4;
        tile[r][tx] = src[(size_t)(r0 + r) * ldin + c0 + tx];
    }
    __syncthreads();
    const int px = tid & 31, cy = tid >> 5;
    #pragma unroll
    for (int i = 0; i < 8; ++i) {
        int cc = cy + i * 8;
        bf16x2 p;
        p[0] = (__bf16)tile[px * 2][cc];
        p[1] = (__bf16)tile[px * 2 + 1][cc];
        *reinterpret_cast<bf16x2*>(&dst[(size_t)(c0 + cc) * ldout + r0 + px * 2]) = p;
    }
}

// ---------------- XCD-banded tile remap (bijective; gy % 8 == 0) ----------------
__device__ __forceinline__ void band_remap(int lin, int gx, int gy, int& bx, int& by) {
    const int band = lin & 7;
    const int idx = lin >> 3;
    bx = idx % gx;
    by = band * (gy >> 3) + idx / gx;
}

// ---------------- one 128x128 GEMM tile (R8 inner loop: 16x16x32, BK=64, swizzled LDS) ----------------
template <int ACT, int CK, int FR>
__device__ __forceinline__ void gemm_tile(const bf16* __restrict__ A, const bf16* __restrict__ Bt,
                                          const float* __restrict__ bias,
                                          bf16* __restrict__ Cb, float* __restrict__ Cf,
                                          int K, long lda, long ldb, long ldc, float scale,
                                          int m0, int n0, bf16* As, bf16* Bs)
{
    const int Kend = CK ? min(K, m0 + 128) : K;
    const int tid = threadIdx.x;
    const int wid = tid >> 6, lane = tid & 63;
    const int wr = wid >> 1, wc = wid & 1;
    const int l15 = lane & 15, quad = lane >> 4;

    const int rloc = lane >> 3, slot = lane & 7;
    const bf16* agp = A + (size_t)(m0 + wid * 32 + rloc) * lda + (slot ^ rloc) * 8;
    const bf16* bgp = Bt + (size_t)(n0 + wid * 32 + rloc) * ldb + (slot ^ rloc) * 8;
    bf16* awb = As + wid * 32 * 64;
    bf16* bwb = Bs + wid * 32 * 64;

    const int afo = (wr * 64 + l15) * 64 + ((quad ^ (l15 & 7)) * 8);
    const int bfo = (wc * 64 + l15) * 64 + ((quad ^ (l15 & 7)) * 8);

    f32x4 acc[4][4];
    #pragma unroll
    for (int i = 0; i < 4; ++i)
        #pragma unroll
        for (int j = 0; j < 4; ++j) acc[i][j] = (f32x4){0.f, 0.f, 0.f, 0.f};

    f32x4 acc_l[4];
    bf16x8 ones;
    if (FR) {
        #pragma unroll
        for (int i = 0; i < 4; ++i) acc_l[i] = (f32x4){0.f, 0.f, 0.f, 0.f};
        #pragma unroll
        for (int i = 0; i < 8; ++i) ones[i] = (__bf16)1.0f;
    }

    for (int k0 = 0; k0 < Kend; k0 += 64) {
        #pragma unroll
        for (int i = 0; i < 4; ++i) {
            gload_lds16(agp + k0 + (size_t)(i * 8) * lda, awb + i * 8 * 64);
            gload_lds16(bgp + k0 + (size_t)(i * 8) * ldb, bwb + i * 8 * 64);
        }
        __syncthreads();

        bf16x8 af0[4], bf0[4], af1[4], bf1[4];
        #pragma unroll
        for (int i = 0; i < 4; ++i) {
            af0[i] = *reinterpret_cast<const bf16x8*>(As + (afo ^ 0)  + i * 1024);
            af1[i] = *reinterpret_cast<const bf16x8*>(As + (afo ^ 32) + i * 1024);
        }
        #pragma unroll
        for (int j = 0; j < 4; ++j) {
            bf0[j] = *reinterpret_cast<const bf16x8*>(Bs + (bfo ^ 0)  + j * 1024);
            bf1[j] = *reinterpret_cast<const bf16x8*>(Bs + (bfo ^ 32) + j * 1024);
        }
        #pragma unroll
        for (int i = 0; i < 4; ++i)
            #pragma unroll
            for (int j = 0; j < 4; ++j)
                acc[i][j] = __builtin_amdgcn_mfma_f32_16x16x32_bf16(af0[i], bf0[j], acc[i][j], 0, 0, 0);
        if (FR) {
            #pragma unroll
            for (int i = 0; i < 4; ++i)
                acc_l[i] = __builtin_amdgcn_mfma_f32_16x16x32_bf16(af0[i], ones, acc_l[i], 0, 0, 0);
        }
        #pragma unroll
        for (int i = 0; i < 4; ++i)
            #pragma unroll
            for (int j = 0; j < 4; ++j)
                acc[i][j] = __builtin_amdgcn_mfma_f32_16x16x32_bf16(af1[i], bf1[j], acc[i][j], 0, 0, 0);
        if (FR) {
            #pragma unroll
            for (int i = 0; i < 4; ++i)
                acc_l[i] = __builtin_amdgcn_mfma_f32_16x16x32_bf16(af1[i], ones, acc_l[i], 0, 0, 0);
        }

        __syncthreads();
    }

    // epilogue: C/D layout row=quad*4+reg, col=l15 (m89/m91-verified)
    #pragma unroll
    for (int i = 0; i < 4; ++i) {
        const int row = m0 + wr * 64 + i * 16 + quad * 4;
        #pragma unroll
        for (int j = 0; j < 4; ++j) {
            const int col = n0 + wc * 64 + j * 16 + l15;
            const float bv = bias ? bias[col] : 0.f;
            #pragma unroll
            for (int r = 0; r < 4; ++r) {
                float vv = scale * acc[i][j][r] + bv;
                if (ACT == 1) vv = fast_gelu(vv);
                else if (ACT == 2)
                    vv = (col <= row + r) ? __builtin_amdgcn_exp2f(1.4426950408889634f * vv) : 0.f;
                if (FR) vv *= __builtin_amdgcn_rcpf(acc_l[i][r]);
                const size_t idx2 = (size_t)(row + r) * ldc + col;
                if (Cf) Cf[idx2] = vv;
                else    Cb[idx2] = f2b(vv);
            }
        }
    }
}

// ---------------- V -> V^T 64x64 tile transpose (within scores phase) ----------------
__device__ __forceinline__ void vtrans_tile(const bf16* __restrict__ ip, bf16* __restrict__ op,
                                            int idx, bf16* smem)
{
    __syncthreads();
    bf16 (*tile)[66] = reinterpret_cast<bf16(*)[66]>(smem);
    const int c0 = (idx & 15) * 64, r0 = (idx >> 4) * 64;
    const int tid = threadIdx.x;
    const int tx = tid & 31, ty = tid >> 5;
    #pragma unroll
    for (int i = 0; i < 8; ++i) {
        int r = ty + i * 8;
        *reinterpret_cast<bf16x2*>(&tile[r][tx * 2]) =
            *reinterpret_cast<const bf16x2*>(&ip[(size_t)(r0 + r) * 3072 + c0 + tx * 2]);
    }
    __syncthreads();
    #pragma unroll
    for (int i = 0; i < 8; ++i) {
        int cc = ty + i * 8;
        bf16x2 p;
        p[0] = tile[tx * 2][cc];
        p[1] = tile[tx * 2 + 1][cc];
        *reinterpret_cast<bf16x2*>(&op[(size_t)(c0 + cc) * 2048 + r0 + tx * 2]) = p;
    }
    __syncthreads();
}

// ---------------- persistent mega-kernel: QKV | scores+vT | attnV | proj | LN2 | MLP1 | MLP2 ----------------
__global__ __launch_bounds__(256, 3)
void mega_kernel(const bf16* __restrict__ h, bf16* __restrict__ kqv, bf16* __restrict__ vT,
                 bf16* __restrict__ attn, bf16* __restrict__ a, bf16* __restrict__ p,
                 bf16* __restrict__ h2, bf16* __restrict__ m, float* __restrict__ out,
                 const bf16* __restrict__ WqkvT, const float* __restrict__ bqkv,
                 const bf16* __restrict__ WprojT, const float* __restrict__ bproj,
                 const float* __restrict__ ln2g, const float* __restrict__ ln2b,
                 const bf16* __restrict__ W1T, const float* __restrict__ b1,
                 const bf16* __restrict__ W2T, const float* __restrict__ b2,
                 unsigned* __restrict__ bar)
{
    __shared__ bf16 As[128 * 64];
    __shared__ bf16 Bs[128 * 64];
    const int blk = blockIdx.x;
    const long T3D = (long)Tq * 3072, TT = (long)Tq * Tq, DT = (long)Dq * Tq, TD = (long)Tq * Dq;

    // P1: kqv = h @ WqkvT + bqkv   (1536 tiles, gx=24 gy=64)
    for (int t = blk; t < 1536; t += NBLK) {
        int bx, by; band_remap(t, 24, 64, bx, by);
        gemm_tile<0,0,0>(h, WqkvT, bqkv, kqv, nullptr, 1024, 1024L, 1024L, 3072L, 1.f,
                         by * 128, bx * 128, As, Bs);
    }
    grid_sync(bar);

    // P2: scores GEMMs on blocks 0..543; all 2048 V->vT transposes on blocks 544..767
    if (blk < 544) {
        const int z = blk / 136, lin = blk % 136;
        int by = (int)((sqrtf(8.f * lin + 1.f) - 1.f) * 0.5f);
        while ((by + 1) * (by + 2) / 2 <= lin) ++by;
        while (by * (by + 1) / 2 > lin) --by;
        const int bx = lin - by * (by + 1) / 2;
        gemm_tile<2,0,0>(kqv + 1024 + (size_t)z * T3D, kqv + (size_t)z * T3D, nullptr,
                         attn + (size_t)z * TT, nullptr, 1024, 3072L, 3072L, 2048L,
                         0.022097086912079608f, by * 128, bx * 128, As, Bs);
    } else {
        for (int j = blk - 544; j < 2048; j += 224) {
            const int z = j >> 9, idx = j & 511;
            vtrans_tile(kqv + 2048 + (size_t)z * T3D, vT + (size_t)z * DT, idx, As);
        }
    }
    grid_sync(bar);

    // P3: a = (P-hat @ V) * rcp(rowsum)   (512 tiles, per z: gx=8 gy=16)
    if (blk < 512) {
        const int z = blk >> 7, lin = blk & 127;
        int bx, by; band_remap(lin, 8, 16, bx, by);
        gemm_tile<0,1,1>(attn + (size_t)z * TT, vT + (size_t)z * DT, nullptr,
                         a + (size_t)z * TD, nullptr, 2048, 2048L, 2048L, 1024L, 1.f,
                         by * 128, bx * 128, As, Bs);
    }
    grid_sync(bar);

    // P4: p = a @ WprojT + bproj   (512 tiles, gx=8 gy=64)
    if (blk < 512) {
        int bx, by; band_remap(blk, 8, 64, bx, by);
        gemm_tile<0,0,0>(a, WprojT, bproj, p, nullptr, 1024, 1024L, 1024L, 1024L, 1.f,
                         by * 128, bx * 128, As, Bs);
    }
    grid_sync(bar);

    // P5: h2 = LN2(p)   (8192 rows)
    for (int r = blk; r < 8192; r += NBLK) {
        ln_body(p, ln2g, ln2b, h2, r, reinterpret_cast<float*>(As));
        __syncthreads();
    }
    grid_sync(bar);

    // P6: m = gelu(h2 @ W1T + b1)   (2048 tiles, gx=32 gy=64)
    for (int t = blk; t < 2048; t += NBLK) {
        int bx, by; band_remap(t, 32, 64, bx, by);
        gemm_tile<1,0,0>(h2, W1T, b1, m, nullptr, 1024, 1024L, 1024L, 4096L, 1.f,
                         by * 128, bx * 128, As, Bs);
    }
    grid_sync(bar);

    // P7: out = m @ W2T + b2   (512 tiles, gx=8 gy=64, fp32 out)
    if (blk < 512) {
        int bx, by; band_remap(blk, 8, 64, bx, by);
        gemm_tile<0,0,0>(m, W2T, b2, nullptr, out, 4096, 4096L, 4096L, 1024L, 1.f,
                         by * 128, bx * 128, As, Bs);
    }
}

extern "C" void kernel_launch(void* const* d_in, const int* in_sizes, int n_in,
                              void* d_out, int out_size, void* d_ws, size_t ws_size,
                              hipStream_t stream)
{
    (void)in_sizes; (void)n_in; (void)out_size; (void)ws_size;
    const float* x     = (const float*)d_in[0];
    const float* ln1g  = (const float*)d_in[1];
    const float* ln1b  = (const float*)d_in[2];
    const float* Wqkv  = (const float*)d_in[3];
    const float* bqkv  = (const float*)d_in[4];
    const float* Wproj = (const float*)d_in[5];
    const float* bproj = (const float*)d_in[6];
    const float* ln2g  = (const float*)d_in[7];
    const float* ln2b  = (const float*)d_in[8];
    const float* W1    = (const float*)d_in[9];
    const float* b1    = (const float*)d_in[10];
    const float* W2    = (const float*)d_in[11];
    const float* b2    = (const float*)d_in[12];
    float* out = (float*)d_out;

    // ---- workspace arena (bf16 elements) ----
    char* ws = (char*)d_ws;
    size_t off = 0;
    auto alloc = [&](size_t elems) { bf16* p = (bf16*)(ws + off); off += elems * sizeof(bf16); return p; };
    bf16* WqkvT  = alloc(3072UL * 1024);
    bf16* WprojT = alloc(1024UL * 1024);
    bf16* W1T    = alloc(4096UL * 1024);
    bf16* W2T    = alloc(1024UL * 4096);
    bf16* h      = alloc(8192UL * 1024);        // LN1 out; later reused as `a`
    bf16* kqv    = alloc(8192UL * 3072);        // per-row k|q|v
    bf16* vT     = alloc(4UL * 1024 * 2048);
    bf16* attn   = alloc(4UL * 2048 * 2048);    // unnormalized exp'd scores
    unsigned* bar = (unsigned*)alloc(64);       // grid barrier (count, generation)
    // aliases (lifetimes disjoint):
    bf16* a   = h;
    bf16* p   = kqv;
    bf16* h2  = kqv + 8192UL * 1024;
    bf16* m   = kqv + 2UL * 8192 * 1024;        // spans kqv-tail + vT + attn

    // prep: LN1 + all 4 weight transposes + barrier init, one dispatch
    prep_kernel<<<11264, 256, 0, stream>>>(x, ln1g, ln1b, h,
                                           Wqkv, WqkvT, Wproj, WprojT, W1, W1T, W2, W2T, bar);

    // everything else: one persistent kernel with device-scope grid barriers
    mega_kernel<<<NBLK, 256, 0, stream>>>(h, kqv, vT, attn, a, p, h2, m, out,
                                          WqkvT, bqkv, WprojT, bproj, ln2g, ln2b,
                                          W1T, b1, W2T, b2, bar);
}

// Round 12
// 469.041 us; speedup vs baseline: 3.4404x; 2.0645x over previous
//
#include <hip/hip_runtime.h>
#include <hip/hip_bf16.h>

typedef __hip_bfloat16 bf16;
typedef __bf16 bf16x8 __attribute__((ext_vector_type(8)));
typedef __bf16 bf16x4 __attribute__((ext_vector_type(4)));
typedef __bf16 bf16x2 __attribute__((ext_vector_type(2)));
typedef float f32x4 __attribute__((ext_vector_type(4)));

static constexpr int Bq = 4, Tq = 2048, Dq = 1024;

__device__ inline float b2f(bf16 h) { return __bfloat162float(h); }
__device__ inline bf16 f2b(float f) { return __float2bfloat16(f); }

// async global->LDS, 16 B per lane. LDS dst = wave-uniform base + lane*16.
__device__ __forceinline__ void gload_lds16(const bf16* g, bf16* lds_wave_base) {
    __builtin_amdgcn_global_load_lds((const __attribute__((address_space(1))) void*)g,
                                     (__attribute__((address_space(3))) void*)lds_wave_base,
                                     16, 0, 0);
}

// fast tanh-approx GELU: x * sigmoid(1.5957691x + 0.0713548x^3), via exp2+rcp
__device__ __forceinline__ float fast_gelu(float x) {
    float u = x * (0.7978845608028654f + 0.03567740814183427f * x * x);
    float e = __builtin_amdgcn_exp2f(-2.885390081777927f * u);
    return x * __builtin_amdgcn_rcpf(1.f + e);
}

__device__ inline void ld4f(const float* p, float* v) {
    float4 t = *reinterpret_cast<const float4*>(p);
    v[0] = t.x; v[1] = t.y; v[2] = t.z; v[3] = t.w;
}
__device__ inline void ld4f(const bf16* p, float* v) {
    bf16x4 t = *reinterpret_cast<const bf16x4*>(p);
    v[0] = (float)t[0]; v[1] = (float)t[1]; v[2] = (float)t[2]; v[3] = (float)t[3];
}

// ---------------- LayerNorm body (one block per row, D=1024), fp32 gamma/beta ----------------
template <typename Tin>
__device__ __forceinline__ void ln_body(const Tin* __restrict__ x, const float* __restrict__ g,
                                        const float* __restrict__ b, bf16* __restrict__ out,
                                        int row, float* sred)
{
    const int tid = threadIdx.x;
    const int s0 = tid * 4;
    const Tin* xr = x + (size_t)row * Dq;
    bf16* orow = out + (size_t)row * Dq;
    float v[4], gv[4], bv[4];
    ld4f(xr + s0, v);
    ld4f(g + s0, gv);
    ld4f(b + s0, bv);
    float sum = v[0] + v[1] + v[2] + v[3];
    float sq = v[0]*v[0] + v[1]*v[1] + v[2]*v[2] + v[3]*v[3];
    for (int o = 32; o > 0; o >>= 1) { sum += __shfl_xor(sum, o); sq += __shfl_xor(sq, o); }
    const int w = tid >> 6;
    if ((tid & 63) == 0) { sred[w] = sum; sred[4 + w] = sq; }
    __syncthreads();
    const float ts = sred[0] + sred[1] + sred[2] + sred[3];
    const float tq = sred[4] + sred[5] + sred[6] + sred[7];
    const float mean = ts / Dq;
    const float rs = rsqrtf(tq / Dq - mean * mean + 1e-5f);
    bf16x4 o4;
    #pragma unroll
    for (int i = 0; i < 4; ++i) o4[i] = (__bf16)((v[i] - mean) * rs * gv[i] + bv[i]);
    *reinterpret_cast<bf16x4*>(orow + s0) = o4;
}

__global__ void ln_kernel(const bf16* __restrict__ x, const float* __restrict__ g,
                          const float* __restrict__ b, bf16* __restrict__ out)
{
    __shared__ float sred[8];
    ln_body(x, g, b, out, blockIdx.x, sred);
}

// ---------------- prep: LN1 (8192 blocks) + 4 weight transposes (3072 tile-blocks) ----------------
__global__ void prep_kernel(const float* __restrict__ x, const float* __restrict__ g,
                            const float* __restrict__ b, bf16* __restrict__ h,
                            const float* __restrict__ Wqkv, bf16* __restrict__ WqkvT,
                            const float* __restrict__ Wproj, bf16* __restrict__ WprojT,
                            const float* __restrict__ W1, bf16* __restrict__ W1T,
                            const float* __restrict__ W2, bf16* __restrict__ W2T)
{
    __shared__ float smem[64 * 65];
    int id = blockIdx.x;
    if (id < 8192) { ln_body(x, g, b, h, id, smem); return; }
    id -= 8192;
    const float* src; bf16* dst; long ldin, ldout; int gx;
    if (id < 768)       { src = Wqkv;  dst = WqkvT;  ldin = 3072; ldout = 1024; gx = 48; }
    else if (id < 1024) { id -= 768;  src = Wproj; dst = WprojT; ldin = 1024; ldout = 1024; gx = 16; }
    else if (id < 2048) { id -= 1024; src = W1;    dst = W1T;    ldin = 4096; ldout = 1024; gx = 64; }
    else                { id -= 2048; src = W2;    dst = W2T;    ldin = 1024; ldout = 4096; gx = 16; }
    const int c0 = (id % gx) * 64, r0 = (id / gx) * 64;
    const int tid = threadIdx.x;
    const int tx = tid & 63, ty = tid >> 6;
    float (*tile)[65] = reinterpret_cast<float(*)[65]>(smem);
    #pragma unroll
    for (int i = 0; i < 16; ++i) {
        int r = ty + i * 4;
        tile[r][tx] = src[(size_t)(r0 + r) * ldin + c0 + tx];
    }
    __syncthreads();
    const int px = tid & 31, cy = tid >> 5;
    #pragma unroll
    for (int i = 0; i < 8; ++i) {
        int cc = cy + i * 8;
        bf16x2 p;
        p[0] = (__bf16)tile[px * 2][cc];
        p[1] = (__bf16)tile[px * 2 + 1][cc];
        *reinterpret_cast<bf16x2*>(&dst[(size_t)(c0 + cc) * ldout + r0 + px * 2]) = p;
    }
}

// ---------------- 128x128 LDS-staged MFMA GEMM, BK=64 (R8 inner loop; best measured) ----------------
// C = act(scale * A @ Bt^T + bias). A:[M,K] (lda), Bt:[N,K] (ldb), bf16.
// ACT: 0 none, 1 gelu, 2 exp2 w/ causal mask. TRI: lower-triangle grid decode;
//      blocks 136..647 of a TRI dispatch do the V->V^T transpose instead (R9-verified fusion).
// CK: truncate K at m0+128 (attn@V). FR: fused row-sum via all-ones-B MFMA.
// LDS tile 128x64 (32 KB, row stride 128 B). Granule slot s at row r holds global
// granule s^(r&7); frag reads measured conflict-free (R8: SQ_LDS_BANK_CONFLICT=0).
template <int ACT, int TRI, int CK, int FR>
__global__ void gemm128(const bf16* __restrict__ A, const bf16* __restrict__ Bt,
                        const float* __restrict__ bias,
                        bf16* __restrict__ Cb, float* __restrict__ Cf,
                        int K, long lda, long ldb, long ldc,
                        long sA, long sB, long sC, float scale,
                        const bf16* __restrict__ vsrc, bf16* __restrict__ vdst)
{
    __shared__ bf16 As[128 * 64];
    __shared__ bf16 Bs[128 * 64];

    int bx, by;
    if (TRI) {
        const int lin = blockIdx.x;
        if (lin >= 136) {
            // ---- fused V -> V^T 64x64 tile transpose (V cols of kqv); 512 tiles/batch ----
            const int idx = lin - 136;
            const int c0 = (idx & 15) * 64, r0 = (idx >> 4) * 64;
            const bf16* ip = vsrc + (size_t)blockIdx.z * ((size_t)Tq * 3072);
            bf16* op = vdst + (size_t)blockIdx.z * ((size_t)Dq * Tq);
            bf16 (*tile)[66] = reinterpret_cast<bf16(*)[66]>(As);
            const int tid = threadIdx.x;
            const int tx = tid & 31, ty = tid >> 5;
            #pragma unroll
            for (int i = 0; i < 8; ++i) {
                int r = ty + i * 8;
                *reinterpret_cast<bf16x2*>(&tile[r][tx * 2]) =
                    *reinterpret_cast<const bf16x2*>(&ip[(size_t)(r0 + r) * 3072 + c0 + tx * 2]);
            }
            __syncthreads();
            #pragma unroll
            for (int i = 0; i < 8; ++i) {
                int cc = ty + i * 8;
                bf16x2 p;
                p[0] = tile[tx * 2][cc];
                p[1] = tile[tx * 2 + 1][cc];
                *reinterpret_cast<bf16x2*>(&op[(size_t)(c0 + cc) * 2048 + r0 + tx * 2]) = p;
            }
            return;
        }
        int t = (int)((sqrtf(8.f * lin + 1.f) - 1.f) * 0.5f);
        while ((t + 1) * (t + 2) / 2 <= lin) ++t;
        while (t * (t + 1) / 2 > lin) --t;
        by = t; bx = lin - t * (t + 1) / 2;
    } else {
        // XCD-banded remap (bijective; gy % 8 == 0 for all our grids)
        const int gx = gridDim.x, gy = gridDim.y;
        const int lin = blockIdx.x + gx * blockIdx.y;
        const int band = lin & 7;
        const int idx = lin >> 3;
        bx = idx % gx;
        by = band * (gy >> 3) + idx / gx;
    }

    const int m0 = by * 128, n0 = bx * 128;
    const int Kend = CK ? min(K, m0 + 128) : K;

    const bf16* Ab = A + (size_t)blockIdx.z * sA;
    const bf16* Bb = Bt + (size_t)blockIdx.z * sB;
    const int tid = threadIdx.x;
    const int wid = tid >> 6, lane = tid & 63;
    const int wr = wid >> 1, wc = wid & 1;
    const int l15 = lane & 15, quad = lane >> 4;

    // staging: wave wid covers rows wid*32 .. +31 in 4 issues of 8 rows.
    // lane: rloc = lane>>3 (row within issue), slot = lane&7; fetches granule slot^rloc.
    const int rloc = lane >> 3, slot = lane & 7;
    const bf16* agp = Ab + (size_t)(m0 + wid * 32 + rloc) * lda + (slot ^ rloc) * 8;
    const bf16* bgp = Bb + (size_t)(n0 + wid * 32 + rloc) * ldb + (slot ^ rloc) * 8;
    bf16* awb = As + wid * 32 * 64;
    bf16* bwb = Bs + wid * 32 * 64;

    // fragment reads: row wr*64+i*16+l15; logical granule sub*4+quad -> slot
    // (sub*4+quad)^(l15&7). sub1 offset = sub0 ^ 32 elems.
    const int afo = (wr * 64 + l15) * 64 + ((quad ^ (l15 & 7)) * 8);
    const int bfo = (wc * 64 + l15) * 64 + ((quad ^ (l15 & 7)) * 8);

    f32x4 acc[4][4];
    #pragma unroll
    for (int i = 0; i < 4; ++i)
        #pragma unroll
        for (int j = 0; j < 4; ++j) acc[i][j] = (f32x4){0.f, 0.f, 0.f, 0.f};

    f32x4 acc_l[4];
    bf16x8 ones;
    if (FR) {
        #pragma unroll
        for (int i = 0; i < 4; ++i) acc_l[i] = (f32x4){0.f, 0.f, 0.f, 0.f};
        #pragma unroll
        for (int i = 0; i < 8; ++i) ones[i] = (__bf16)1.0f;
    }

    for (int k0 = 0; k0 < Kend; k0 += 64) {
        #pragma unroll
        for (int i = 0; i < 4; ++i) {
            gload_lds16(agp + k0 + (size_t)(i * 8) * lda, awb + i * 8 * 64);
            gload_lds16(bgp + k0 + (size_t)(i * 8) * ldb, bwb + i * 8 * 64);
        }
        __syncthreads();   // drains vmcnt: LDS tile complete

        bf16x8 af0[4], bf0[4], af1[4], bf1[4];
        #pragma unroll
        for (int i = 0; i < 4; ++i) {
            af0[i] = *reinterpret_cast<const bf16x8*>(As + (afo ^ 0)  + i * 1024);
            af1[i] = *reinterpret_cast<const bf16x8*>(As + (afo ^ 32) + i * 1024);
        }
        #pragma unroll
        for (int j = 0; j < 4; ++j) {
            bf0[j] = *reinterpret_cast<const bf16x8*>(Bs + (bfo ^ 0)  + j * 1024);
            bf1[j] = *reinterpret_cast<const bf16x8*>(Bs + (bfo ^ 32) + j * 1024);
        }
        #pragma unroll
        for (int i = 0; i < 4; ++i)
            #pragma unroll
            for (int j = 0; j < 4; ++j)
                acc[i][j] = __builtin_amdgcn_mfma_f32_16x16x32_bf16(af0[i], bf0[j], acc[i][j], 0, 0, 0);
        if (FR) {
            #pragma unroll
            for (int i = 0; i < 4; ++i)
                acc_l[i] = __builtin_amdgcn_mfma_f32_16x16x32_bf16(af0[i], ones, acc_l[i], 0, 0, 0);
        }
        #pragma unroll
        for (int i = 0; i < 4; ++i)
            #pragma unroll
            for (int j = 0; j < 4; ++j)
                acc[i][j] = __builtin_amdgcn_mfma_f32_16x16x32_bf16(af1[i], bf1[j], acc[i][j], 0, 0, 0);
        if (FR) {
            #pragma unroll
            for (int i = 0; i < 4; ++i)
                acc_l[i] = __builtin_amdgcn_mfma_f32_16x16x32_bf16(af1[i], ones, acc_l[i], 0, 0, 0);
        }

        __syncthreads();   // protect LDS before next iteration overwrites
    }

    // epilogue: C/D layout row=quad*4+reg, col=l15 (m89/m91-verified)
    #pragma unroll
    for (int i = 0; i < 4; ++i) {
        const int row = m0 + wr * 64 + i * 16 + quad * 4;
        #pragma unroll
        for (int j = 0; j < 4; ++j) {
            const int col = n0 + wc * 64 + j * 16 + l15;
            const float bv = bias ? bias[col] : 0.f;
            #pragma unroll
            for (int r = 0; r < 4; ++r) {
                float vv = scale * acc[i][j][r] + bv;
                if (ACT == 1) vv = fast_gelu(vv);
                else if (ACT == 2)
                    vv = (col <= row + r) ? __builtin_amdgcn_exp2f(1.4426950408889634f * vv) : 0.f;
                if (FR) vv *= __builtin_amdgcn_rcpf(acc_l[i][r]);
                const size_t idx2 = (size_t)(row + r) * ldc + col + (size_t)blockIdx.z * sC;
                if (Cf) Cf[idx2] = vv;
                else    Cb[idx2] = f2b(vv);
            }
        }
    }
}

extern "C" void kernel_launch(void* const* d_in, const int* in_sizes, int n_in,
                              void* d_out, int out_size, void* d_ws, size_t ws_size,
                              hipStream_t stream)
{
    (void)in_sizes; (void)n_in; (void)out_size; (void)ws_size;
    const float* x     = (const float*)d_in[0];
    const float* ln1g  = (const float*)d_in[1];
    const float* ln1b  = (const float*)d_in[2];
    const float* Wqkv  = (const float*)d_in[3];
    const float* bqkv  = (const float*)d_in[4];
    const float* Wproj = (const float*)d_in[5];
    const float* bproj = (const float*)d_in[6];
    const float* ln2g  = (const float*)d_in[7];
    const float* ln2b  = (const float*)d_in[8];
    const float* W1    = (const float*)d_in[9];
    const float* b1    = (const float*)d_in[10];
    const float* W2    = (const float*)d_in[11];
    const float* b2    = (const float*)d_in[12];
    float* out = (float*)d_out;

    // ---- workspace arena (bf16 elements) ----
    char* ws = (char*)d_ws;
    size_t off = 0;
    auto alloc = [&](size_t elems) { bf16* p = (bf16*)(ws + off); off += elems * sizeof(bf16); return p; };
    bf16* WqkvT  = alloc(3072UL * 1024);
    bf16* WprojT = alloc(1024UL * 1024);
    bf16* W1T    = alloc(4096UL * 1024);
    bf16* W2T    = alloc(1024UL * 4096);
    bf16* h      = alloc(8192UL * 1024);        // LN1 out; later reused as `a`
    bf16* kqv    = alloc(8192UL * 3072);        // per-row k|q|v
    bf16* vT     = alloc(4UL * 1024 * 2048);
    bf16* attn   = alloc(4UL * 2048 * 2048);    // unnormalized exp'd scores
    // aliases (lifetimes disjoint):
    bf16* a   = h;
    bf16* p   = kqv;
    bf16* h2  = kqv + 8192UL * 1024;
    bf16* m   = kqv + 2UL * 8192 * 1024;        // spans kqv-tail + vT + attn

    const long T3D = (long)Tq * 3072, TT = (long)Tq * Tq, DT = (long)Dq * Tq, TD = (long)Tq * Dq;

    // prep: LN1 + all 4 weight transposes in one dispatch
    prep_kernel<<<11264, 256, 0, stream>>>(x, ln1g, ln1b, h,
                                           Wqkv, WqkvT, Wproj, WprojT, W1, W1T, W2, W2T);

    // kqv = h @ Wqkv + bqkv    [8192, 3072]
    gemm128<0,0,0,0><<<dim3(24, 64, 1), 256, 0, stream>>>(h, WqkvT, bqkv, kqv, nullptr,
        1024, 1024L, 1024L, 3072L, 0L, 0L, 0L, 1.f, nullptr, nullptr);

    // P-hat = exp(q @ k^T / sqrt(T)) causal, triangular grid (136 tiles/batch)
    // + fused V->V^T transpose in blocks 136..647
    gemm128<2,1,0,0><<<dim3(648, 1, 4), 256, 0, stream>>>(kqv + 1024, kqv, nullptr, attn, nullptr,
        1024, 3072L, 3072L, 2048L, T3D, T3D, TT, 0.022097086912079608f, kqv + 2048, vT);

    // a = (P-hat @ V) * rcp(rowsum)   (K truncated to m0+128; rowsum fused via ones-MFMA)
    gemm128<0,0,1,1><<<dim3(8, 16, 4), 256, 0, stream>>>(attn, vT, nullptr, a, nullptr,
        2048, 2048L, 2048L, 1024L, TT, DT, TD, 1.f, nullptr, nullptr);

    // p = a @ Wproj + bproj
    gemm128<0,0,0,0><<<dim3(8, 64, 1), 256, 0, stream>>>(a, WprojT, bproj, p, nullptr,
        1024, 1024L, 1024L, 1024L, 0L, 0L, 0L, 1.f, nullptr, nullptr);

    ln_kernel<<<8192, 256, 0, stream>>>(p, ln2g, ln2b, h2);

    // m = gelu(h2 @ W1 + b1)   [8192, 4096]
    gemm128<1,0,0,0><<<dim3(32, 64, 1), 256, 0, stream>>>(h2, W1T, b1, m, nullptr,
        1024, 1024L, 1024L, 4096L, 0L, 0L, 0L, 1.f, nullptr, nullptr);

    // out = m @ W2 + b2        [8192, 1024]  (fp32 out)
    gemm128<0,0,0,0><<<dim3(8, 64, 1), 256, 0, stream>>>(m, W2T, b2, nullptr, out,
        4096, 4096L, 4096L, 1024L, 0L, 0L, 0L, 1.f, nullptr, nullptr);
}